// Round 9
// baseline (130.526 us; speedup 1.0000x reference)
//
#include <hip/hip_runtime.h>

typedef __attribute__((ext_vector_type(8))) short short8;
typedef __attribute__((ext_vector_type(4))) float floatx4;
typedef __attribute__((ext_vector_type(4))) float f32x4;

#define BS   32768

__device__ __forceinline__ unsigned short f2bf(float f) {
  unsigned int u = __float_as_uint(f);
  u += 0x7fffu + ((u >> 16) & 1u);   // round-to-nearest-even
  return (unsigned short)(u >> 16);
}

// Transpose We [8][512][256] f32 -> WeT [8][256][512] bf16 (k-contiguous rows)
__global__ void prep_weT(const float* __restrict__ We, unsigned short* __restrict__ WeT) {
  int e  = blockIdx.x >> 6;
  int kc = blockIdx.x & 63;
  int h  = threadIdx.x;
  short8 pk;
#pragma unroll
  for (int j = 0; j < 8; ++j)
    pk[j] = (short)f2bf(We[e * 131072 + (kc * 8 + j) * 256 + h]);
  *reinterpret_cast<short8*>(&WeT[e * 131072 + h * 512 + kc * 8]) = pk;
}

// Wg [2][512][8] f32 -> WgT [16][512] bf16, row = t*8+e
__global__ void prep_wgT(const float* __restrict__ Wg, unsigned short* __restrict__ WgT) {
  int row = blockIdx.x;
  int t = row >> 3, e = row & 7;
  int lane = threadIdx.x;
  short8 pk;
#pragma unroll
  for (int j = 0; j < 8; ++j)
    pk[j] = (short)f2bf(Wg[t * 4096 + (lane * 8 + j) * 8 + e]);
  *reinterpret_cast<short8*>(&WgT[row * 512 + lane * 8]) = pk;
}

#define GLOAD16(SRC, DST) \
  __builtin_amdgcn_global_load_lds( \
      (const __attribute__((address_space(1))) unsigned int*)(SRC), \
      (__attribute__((address_space(3))) unsigned int*)(DST), 16, 0, 0)

// kernel2: convert xv -> Abf (bf16, pre-swizzled 32KB chunks [mt][kc][256r][64k])
// and compute gates -> gates_ws[16][32768] (col-major planes, col = t*8+e).
// 512 blocks x 256 thr; block handles 64 rows.
__global__ __launch_bounds__(256) void conv_gates(
    const float* __restrict__ xv, const unsigned short* __restrict__ WgT,
    const float* __restrict__ bg, unsigned short* __restrict__ Abf,
    float* __restrict__ gates_ws)
{
  __shared__ __attribute__((aligned(16))) unsigned char bufA[65536]; // 64r x 1024B, swizzled
  const int tid = threadIdx.x;
  const int b0  = blockIdx.x * 64;
  const int r8 = tid >> 3, kslot = tid & 7;
  const int mt = b0 >> 8;
  const int rc_base = b0 & 255;
  unsigned char* AbfB = reinterpret_cast<unsigned char*>(Abf);

#pragma unroll
  for (int pass = 0; pass < 2; ++pass) {
    int r = pass * 32 + r8;                 // local row 0..63
    int r_c = rc_base + r;                  // row within 256-row m-tile
    const float* xrow = xv + (size_t)(b0 + r) * 512;
    unsigned swz = (unsigned)((r & 7) << 4);
#pragma unroll
    for (int j = 0; j < 8; ++j) {           // j = k-chunk (64 k each)
      int o = j * 8 + kslot;                // k-octet index 0..63
      f32x4 v0 = *reinterpret_cast<const f32x4*>(xrow + o * 8);
      f32x4 v1 = *reinterpret_cast<const f32x4*>(xrow + o * 8 + 4);
      short8 pk;
      pk[0] = (short)f2bf(v0[0]); pk[1] = (short)f2bf(v0[1]);
      pk[2] = (short)f2bf(v0[2]); pk[3] = (short)f2bf(v0[3]);
      pk[4] = (short)f2bf(v1[0]); pk[5] = (short)f2bf(v1[1]);
      pk[6] = (short)f2bf(v1[2]); pk[7] = (short)f2bf(v1[3]);
      // LDS copy (v8 bufA layout: 1024B rows)
      unsigned lb = ((unsigned)r << 10) + (((unsigned)(o * 16)) ^ swz);
      *reinterpret_cast<short8*>(&bufA[lb]) = pk;
      // global pre-swizzled chunk (128B rows)
      unsigned gb = (unsigned)((mt * 8 + j) * 32768) + (unsigned)(r_c * 128)
                  + (((unsigned)(kslot * 16)) ^ swz);
      *reinterpret_cast<short8*>(&AbfB[gb]) = pk;
    }
  }
  __syncthreads();

  // gates: 4 waves, wave = m-frag (16 rows each); softmax over experts per t
  const int wave = tid >> 6, lane = tid & 63;
  const int row16 = lane & 15, kgrp = lane >> 4;
  floatx4 gacc = {0.f, 0.f, 0.f, 0.f};
  const unsigned abase = ((unsigned)row16 << 10) + ((unsigned)kgrp << 4) + ((unsigned)wave << 14);
  const unsigned a_swz = (unsigned)((row16 & 7) << 4);
  const unsigned short* wg_lane = WgT + row16 * 512 + kgrp * 8;
#pragma unroll
  for (int ks = 0; ks < 16; ++ks) {
    short8 af = *reinterpret_cast<const short8*>(&bufA[(abase + (unsigned)(ks << 6)) ^ a_swz]);
    short8 bf = *reinterpret_cast<const short8*>(wg_lane + ks * 32);
    gacc = __builtin_amdgcn_mfma_f32_16x16x32_bf16(af, bf, gacc, 0, 0, 0);
  }
  float bgv = bg[row16];
#pragma unroll
  for (int j = 0; j < 4; ++j) {
    float v = gacc[j] + bgv;
    float mx = v;
    mx = fmaxf(mx, __shfl_xor(mx, 1));
    mx = fmaxf(mx, __shfl_xor(mx, 2));
    mx = fmaxf(mx, __shfl_xor(mx, 4));
    float p = __expf(v - mx);
    float s = p;
    s += __shfl_xor(s, 1);
    s += __shfl_xor(s, 2);
    s += __shfl_xor(s, 4);
    gates_ws[row16 * BS + b0 + wave * 16 + kgrp * 4 + j] = p / s;
  }
}

// main: grid 1024 (mt = bid>>3, e = bid&7). Block tile 256r x 256h (one expert),
// 8 K-steps of 64. 8 waves 2m x 4n; wave tile 128x64 = 8 m-frags x 4 n-frags.
// A+B double-buffered via global_load_lds (pre-swizzled sources), counted vmcnt(8).
__global__ __launch_bounds__(512, 2) void mmoe_main(
    const unsigned short* __restrict__ Abf,   // [128][8][16384] elems
    const unsigned short* __restrict__ WeT,   // [8][256][512]
    const float* __restrict__ gates_ws,       // [16][32768]
    const float* __restrict__ be,             // [8][256]
    const float* __restrict__ Wt,             // [2][256]
    float* __restrict__ acc_ws)               // [2][32768]
{
  __shared__ __attribute__((aligned(16))) unsigned char smem[131072]; // A0|A1|B0|B1 (32KB each)
  __shared__ float red_lds[4][256][2];

  const int tid = threadIdx.x, wave = tid >> 6, lane = tid & 63;
  const int row16 = lane & 15, kgrp = lane >> 4;
  const int wm = wave >> 2, wn = wave & 3;
  const int bid = blockIdx.x, e = bid & 7, mt = bid >> 3;

  const unsigned short* Asrc = Abf + (size_t)mt * 131072;
  const unsigned short* Bsrc = WeT + e * 131072;

  unsigned soffB[4];
#pragma unroll
  for (int i = 0; i < 4; ++i) {
    unsigned x = (unsigned)(i * 8192 + tid * 16);
    unsigned r = x >> 7;
    unsigned y = (x & 127u) ^ ((r & 7u) << 4);
    soffB[i] = r * 512u + (y >> 1);
  }
  const unsigned soffA0 = (unsigned)(tid * 8);   // + i*4096 (linear byte-match copy)

  unsigned char* Ab0 = smem;
  unsigned char* Ab1 = smem + 32768;
  unsigned char* Bb0 = smem + 65536;
  unsigned char* Bb1 = smem + 98304;

  // prologue: stage(0)
#pragma unroll
  for (int i = 0; i < 4; ++i)
    GLOAD16(Asrc + (i * 4096 + soffA0), Ab0 + (i * 8 + wave) * 1024);
#pragma unroll
  for (int i = 0; i < 4; ++i)
    GLOAD16(Bsrc + soffB[i], Bb0 + (i * 8 + wave) * 1024);

  floatx4 acc[8][4];
#pragma unroll
  for (int mf = 0; mf < 8; ++mf)
#pragma unroll
    for (int n = 0; n < 4; ++n) acc[mf][n] = (floatx4){0.f, 0.f, 0.f, 0.f};

  const unsigned swz = (unsigned)((row16 & 7) << 4);
  const unsigned bcol = (unsigned)(wn * 64 + row16);
  const unsigned arow = (unsigned)(wm * 128 + row16);

  for (int kc = 0; kc < 8; ++kc) {
    const int cur = kc & 1;
    if (kc < 7) {
      unsigned char* an = cur ? Ab0 : Ab1;
      unsigned char* bn = cur ? Bb0 : Bb1;
      const unsigned short* abase2 = Asrc + (kc + 1) * 16384;
      const unsigned short* bbase2 = Bsrc + (kc + 1) * 64;
#pragma unroll
      for (int i = 0; i < 4; ++i)
        GLOAD16(abase2 + (i * 4096 + soffA0), an + (i * 8 + wave) * 1024);
#pragma unroll
      for (int i = 0; i < 4; ++i)
        GLOAD16(bbase2 + soffB[i], bn + (i * 8 + wave) * 1024);
      asm volatile("s_waitcnt vmcnt(8)" ::: "memory");  // stage(kc) landed; stage(kc+1) in flight
    } else {
      asm volatile("s_waitcnt vmcnt(0)" ::: "memory");
    }
    __builtin_amdgcn_s_barrier();
    __builtin_amdgcn_sched_barrier(0);

    const unsigned char* ab = cur ? Ab1 : Ab0;
    const unsigned char* bb = cur ? Bb1 : Bb0;
    __builtin_amdgcn_s_setprio(1);
    short8 bf[2][4];
#pragma unroll
    for (int ks = 0; ks < 2; ++ks)
#pragma unroll
      for (int n = 0; n < 4; ++n)
        bf[ks][n] = *reinterpret_cast<const short8*>(
            &bb[(bcol + (unsigned)(n * 16)) * 128 + (((unsigned)(ks * 64 + kgrp * 16)) ^ swz)]);
#pragma unroll
    for (int mf = 0; mf < 8; ++mf) {
      const unsigned rb = (arow + (unsigned)(mf * 16)) * 128;
      short8 a0 = *reinterpret_cast<const short8*>(&ab[rb + (((unsigned)(kgrp * 16)) ^ swz)]);
      short8 a1 = *reinterpret_cast<const short8*>(&ab[rb + (((unsigned)(64 + kgrp * 16)) ^ swz)]);
#pragma unroll
      for (int n = 0; n < 4; ++n)
        acc[mf][n] = __builtin_amdgcn_mfma_f32_16x16x32_bf16(a0, bf[0][n], acc[mf][n], 0, 0, 0);
#pragma unroll
      for (int n = 0; n < 4; ++n)
        acc[mf][n] = __builtin_amdgcn_mfma_f32_16x16x32_bf16(a1, bf[1][n], acc[mf][n], 0, 0, 0);
    }
    __builtin_amdgcn_s_setprio(0);
    __builtin_amdgcn_s_barrier();
  }

  // epilogue: bias+relu -> Wt-dot -> col reduce -> wn reduce -> gate -> atomicAdd
  float bev[4], wtv[2][4];
#pragma unroll
  for (int n = 0; n < 4; ++n) bev[n] = be[e * 256 + wn * 64 + n * 16 + row16];
#pragma unroll
  for (int t = 0; t < 2; ++t)
#pragma unroll
    for (int n = 0; n < 4; ++n) wtv[t][n] = Wt[t * 256 + wn * 64 + n * 16 + row16];

#pragma unroll
  for (int mf = 0; mf < 8; ++mf) {
#pragma unroll
    for (int j = 0; j < 4; ++j) {
      float p0 = 0.f, p1 = 0.f;
#pragma unroll
      for (int n = 0; n < 4; ++n) {
        float r = fmaxf(acc[mf][n][j] + bev[n], 0.f);
        p0 = fmaf(r, wtv[0][n], p0);
        p1 = fmaf(r, wtv[1][n], p1);
      }
      p0 += __shfl_xor(p0, 1); p1 += __shfl_xor(p1, 1);
      p0 += __shfl_xor(p0, 2); p1 += __shfl_xor(p1, 2);
      p0 += __shfl_xor(p0, 4); p1 += __shfl_xor(p1, 4);
      p0 += __shfl_xor(p0, 8); p1 += __shfl_xor(p1, 8);
      if (row16 == 0) {
        int rw = wm * 128 + mf * 16 + kgrp * 4 + j;
        red_lds[wn][rw][0] = p0;
        red_lds[wn][rw][1] = p1;
      }
    }
  }
  __syncthreads();

  {
    int row = tid >> 1, t = tid & 1;
    float s = red_lds[0][row][t] + red_lds[1][row][t]
            + red_lds[2][row][t] + red_lds[3][row][t];
    float g = gates_ws[(t * 8 + e) * BS + mt * 256 + row];
    atomicAdd(&acc_ws[t * BS + mt * 256 + row], s * g);
  }
}

__global__ void finalize(const float* __restrict__ acc_ws, const float* __restrict__ bt,
                         float* __restrict__ out) {
  int i = blockIdx.x * 256 + threadIdx.x;   // 65536
  int t = i >> 15;
  float s = fmaxf(acc_ws[i] + bt[t], 0.f);
  out[i] = 1.f / (1.f + __expf(-s));
}

extern "C" void kernel_launch(void* const* d_in, const int* in_sizes, int n_in,
                              void* d_out, int out_size, void* d_ws, size_t ws_size,
                              hipStream_t stream) {
  const float* xv = (const float*)d_in[0];
  const float* We = (const float*)d_in[1];
  const float* be = (const float*)d_in[2];
  const float* Wg = (const float*)d_in[3];
  const float* bg = (const float*)d_in[4];
  const float* Wt = (const float*)d_in[5];
  const float* bt = (const float*)d_in[6];
  float* out = (float*)d_out;

  unsigned char* ws = (unsigned char*)d_ws;
  unsigned short* WeT      = (unsigned short*)(ws);                     // 2 MiB
  unsigned short* WgT      = (unsigned short*)(ws + (2u << 20));        // 16 KiB
  unsigned short* Abf      = (unsigned short*)(ws + (4u << 20));        // 32 MiB
  float*          gates_ws = (float*)(ws + (36u << 20));                // 2 MiB
  float*          acc_ws   = (float*)(ws + (38u << 20));                // 256 KiB

  hipMemsetAsync(acc_ws, 0, 2 * BS * sizeof(float), stream);
  prep_weT<<<512, 256, 0, stream>>>(We, WeT);
  prep_wgT<<<16, 64, 0, stream>>>(Wg, WgT);
  conv_gates<<<512, 256, 0, stream>>>(xv, WgT, bg, Abf, gates_ws);
  mmoe_main<<<1024, 512, 0, stream>>>(Abf, WeT, gates_ws, be, Wt, acc_ws);
  finalize<<<256, 256, 0, stream>>>(acc_ws, bt, out);
}

// Round 10
// 124.936 us; speedup vs baseline: 1.0447x; 1.0447x over previous
//
#include <hip/hip_runtime.h>

typedef __attribute__((ext_vector_type(8))) short short8;
typedef __attribute__((ext_vector_type(4))) float floatx4;
typedef __attribute__((ext_vector_type(4))) float f32x4;

#define BS   32768

__device__ __forceinline__ unsigned short f2bf(float f) {
  unsigned int u = __float_as_uint(f);
  u += 0x7fffu + ((u >> 16) & 1u);   // round-to-nearest-even
  return (unsigned short)(u >> 16);
}

// Transpose We [8][512][256] f32 -> WeT [8][256][512] bf16 (k-contiguous rows)
__global__ void prep_weT(const float* __restrict__ We, unsigned short* __restrict__ WeT) {
  int e  = blockIdx.x >> 6;
  int kc = blockIdx.x & 63;
  int h  = threadIdx.x;
  short8 pk;
#pragma unroll
  for (int j = 0; j < 8; ++j)
    pk[j] = (short)f2bf(We[e * 131072 + (kc * 8 + j) * 256 + h]);
  *reinterpret_cast<short8*>(&WeT[e * 131072 + h * 512 + kc * 8]) = pk;
}

// Wg [2][512][8] f32 -> WgT [16][512] bf16, row = t*8+e
__global__ void prep_wgT(const float* __restrict__ Wg, unsigned short* __restrict__ WgT) {
  int row = blockIdx.x;
  int t = row >> 3, e = row & 7;
  int lane = threadIdx.x;
  short8 pk;
#pragma unroll
  for (int j = 0; j < 8; ++j)
    pk[j] = (short)f2bf(Wg[t * 4096 + (lane * 8 + j) * 8 + e]);
  *reinterpret_cast<short8*>(&WgT[row * 512 + lane * 8]) = pk;
}

#define GLOAD16(SRC, DST) \
  __builtin_amdgcn_global_load_lds( \
      (const __attribute__((address_space(1))) unsigned int*)(SRC), \
      (__attribute__((address_space(3))) unsigned int*)(DST), 16, 0, 0)

// kernel2: convert xv -> Abf (bf16, pre-swizzled 32KB chunks [mt][kc][256r][64k])
// and compute gates -> gates_ws[16][32768] (col-major planes, col = t*8+e).
__global__ __launch_bounds__(256) void conv_gates(
    const float* __restrict__ xv, const unsigned short* __restrict__ WgT,
    const float* __restrict__ bg, unsigned short* __restrict__ Abf,
    float* __restrict__ gates_ws)
{
  __shared__ __attribute__((aligned(16))) unsigned char bufA[65536]; // 64r x 1024B, swizzled
  const int tid = threadIdx.x;
  const int b0  = blockIdx.x * 64;
  const int r8 = tid >> 3, kslot = tid & 7;
  const int mt = b0 >> 8;
  const int rc_base = b0 & 255;
  unsigned char* AbfB = reinterpret_cast<unsigned char*>(Abf);

#pragma unroll
  for (int pass = 0; pass < 2; ++pass) {
    int r = pass * 32 + r8;                 // local row 0..63
    int r_c = rc_base + r;                  // row within 256-row m-tile
    const float* xrow = xv + (size_t)(b0 + r) * 512;
    unsigned swz = (unsigned)((r & 7) << 4);
#pragma unroll
    for (int j = 0; j < 8; ++j) {           // j = k-chunk (64 k each)
      int o = j * 8 + kslot;                // k-octet index 0..63
      f32x4 v0 = *reinterpret_cast<const f32x4*>(xrow + o * 8);
      f32x4 v1 = *reinterpret_cast<const f32x4*>(xrow + o * 8 + 4);
      short8 pk;
      pk[0] = (short)f2bf(v0[0]); pk[1] = (short)f2bf(v0[1]);
      pk[2] = (short)f2bf(v0[2]); pk[3] = (short)f2bf(v0[3]);
      pk[4] = (short)f2bf(v1[0]); pk[5] = (short)f2bf(v1[1]);
      pk[6] = (short)f2bf(v1[2]); pk[7] = (short)f2bf(v1[3]);
      unsigned lb = ((unsigned)r << 10) + (((unsigned)(o * 16)) ^ swz);
      *reinterpret_cast<short8*>(&bufA[lb]) = pk;
      unsigned gb = (unsigned)((mt * 8 + j) * 32768) + (unsigned)(r_c * 128)
                  + (((unsigned)(kslot * 16)) ^ swz);
      *reinterpret_cast<short8*>(&AbfB[gb]) = pk;
    }
  }
  __syncthreads();

  const int wave = tid >> 6, lane = tid & 63;
  const int row16 = lane & 15, kgrp = lane >> 4;
  floatx4 gacc = {0.f, 0.f, 0.f, 0.f};
  const unsigned abase = ((unsigned)row16 << 10) + ((unsigned)kgrp << 4) + ((unsigned)wave << 14);
  const unsigned a_swz = (unsigned)((row16 & 7) << 4);
  const unsigned short* wg_lane = WgT + row16 * 512 + kgrp * 8;
#pragma unroll
  for (int ks = 0; ks < 16; ++ks) {
    short8 af = *reinterpret_cast<const short8*>(&bufA[(abase + (unsigned)(ks << 6)) ^ a_swz]);
    short8 bf = *reinterpret_cast<const short8*>(wg_lane + ks * 32);
    gacc = __builtin_amdgcn_mfma_f32_16x16x32_bf16(af, bf, gacc, 0, 0, 0);
  }
  float bgv = bg[row16];
#pragma unroll
  for (int j = 0; j < 4; ++j) {
    float v = gacc[j] + bgv;
    float mx = v;
    mx = fmaxf(mx, __shfl_xor(mx, 1));
    mx = fmaxf(mx, __shfl_xor(mx, 2));
    mx = fmaxf(mx, __shfl_xor(mx, 4));
    float p = __expf(v - mx);
    float s = p;
    s += __shfl_xor(s, 1);
    s += __shfl_xor(s, 2);
    s += __shfl_xor(s, 4);
    gates_ws[row16 * BS + b0 + wave * 16 + kgrp * 4 + j] = p / s;
  }
}

// main: grid 1024 (mt = bid>>3, e = bid&7). Block tile 256r x 256h (one expert),
// K = 8 kt of 64. 8 waves 2m x 4n; wave tile 128x64. v10: m201-style 4-phase
// per kt (16 MFMA/phase), early-issued stages (A in ph0, B in ph1), fenced
// lgkmcnt(0) per phase, setprio around MFMA, vmcnt(0) only at ph3 (>=2 phases
// after issue -> nearly free).
__global__ __launch_bounds__(512, 2) void mmoe_main(
    const unsigned short* __restrict__ Abf,   // [128][8][16384] elems, pre-swizzled
    const unsigned short* __restrict__ WeT,   // [8][256][512]
    const float* __restrict__ gates_ws,       // [16][32768]
    const float* __restrict__ be,             // [8][256]
    const float* __restrict__ Wt,             // [2][256]
    float* __restrict__ acc_ws)               // [2][32768]
{
  __shared__ __attribute__((aligned(16))) unsigned char smem[131072]; // A0|A1|B0|B1 (32KB each)
  __shared__ float red_lds[4][256][2];

  const int tid = threadIdx.x, wave = tid >> 6, lane = tid & 63;
  const int row16 = lane & 15, kgrp = lane >> 4;
  const int wm = wave >> 2, wn = wave & 3;
  const int bid = blockIdx.x, e = bid & 7, mt = bid >> 3;

  const unsigned short* Asrc = Abf + (size_t)mt * 131072;
  const unsigned short* Bsrc = WeT + e * 131072;

  unsigned soffB[4];
#pragma unroll
  for (int i = 0; i < 4; ++i) {
    unsigned x = (unsigned)(i * 8192 + tid * 16);
    unsigned r = x >> 7;
    unsigned y = (x & 127u) ^ ((r & 7u) << 4);
    soffB[i] = r * 512u + (y >> 1);
  }
  const unsigned soffA0 = (unsigned)(tid * 8);   // linear byte-match copy (pre-swizzled src)

  unsigned char* Ab0 = smem;
  unsigned char* Ab1 = smem + 32768;
  unsigned char* Bb0 = smem + 65536;
  unsigned char* Bb1 = smem + 98304;

  // prologue: stage kt0 fully, drain, barrier
#pragma unroll
  for (int i = 0; i < 4; ++i)
    GLOAD16(Asrc + (i * 4096 + soffA0), Ab0 + (i * 8 + wave) * 1024);
#pragma unroll
  for (int i = 0; i < 4; ++i)
    GLOAD16(Bsrc + soffB[i], Bb0 + (i * 8 + wave) * 1024);
  asm volatile("s_waitcnt vmcnt(0)" ::: "memory");
  __syncthreads();

  floatx4 acc[8][4];
#pragma unroll
  for (int mf = 0; mf < 8; ++mf)
#pragma unroll
    for (int n = 0; n < 4; ++n) acc[mf][n] = (floatx4){0.f, 0.f, 0.f, 0.f};

  const unsigned swz  = (unsigned)((row16 & 7) << 4);
  const unsigned bcol = (unsigned)(wn * 64 + row16);
  const unsigned arow = (unsigned)(wm * 128 + row16);

  for (int kt = 0; kt < 8; ++kt) {
    __builtin_amdgcn_sched_barrier(0);   // fence: no ds_read hoist across kt boundary
    const int cur = kt & 1;
    const unsigned char* ab = cur ? Ab1 : Ab0;
    const unsigned char* bb = cur ? Bb1 : Bb0;
    unsigned char* an = cur ? Ab0 : Ab1;
    unsigned char* bn = cur ? Bb0 : Bb1;
    const unsigned short* aNext = Asrc + (kt + 1) * 16384;
    const unsigned short* bNext = Bsrc + (kt + 1) * 64;

    auto rdA = [&](int mf, int ks) -> short8 {
      const unsigned rb = (arow + (unsigned)(mf * 16)) * 128;
      return *reinterpret_cast<const short8*>(
          &ab[rb + (((unsigned)(ks * 64 + kgrp * 16)) ^ swz)]);
    };

    short8 bf[2][4];

    // ---------- phase 0: ds B(all 8) + A(mf0,1); stage A(kt+1) ----------
    {
#pragma unroll
      for (int ks = 0; ks < 2; ++ks)
#pragma unroll
        for (int n = 0; n < 4; ++n)
          bf[ks][n] = *reinterpret_cast<const short8*>(
              &bb[(bcol + (unsigned)(n * 16)) * 128 + (((unsigned)(ks * 64 + kgrp * 16)) ^ swz)]);
      short8 p00 = rdA(0, 0), p01 = rdA(0, 1), p10 = rdA(1, 0), p11 = rdA(1, 1);
      if (kt < 7) {
#pragma unroll
        for (int i = 0; i < 4; ++i)
          GLOAD16(aNext + (i * 4096 + soffA0), an + (i * 8 + wave) * 1024);
      }
      asm volatile("s_waitcnt lgkmcnt(8)" ::: "memory");
      __builtin_amdgcn_s_barrier();
      asm volatile("s_waitcnt lgkmcnt(0)" ::: "memory");
      __builtin_amdgcn_sched_barrier(0);
      __builtin_amdgcn_s_setprio(1);
#pragma unroll
      for (int n = 0; n < 4; ++n)
        acc[0][n] = __builtin_amdgcn_mfma_f32_16x16x32_bf16(p00, bf[0][n], acc[0][n], 0, 0, 0);
#pragma unroll
      for (int n = 0; n < 4; ++n)
        acc[0][n] = __builtin_amdgcn_mfma_f32_16x16x32_bf16(p01, bf[1][n], acc[0][n], 0, 0, 0);
#pragma unroll
      for (int n = 0; n < 4; ++n)
        acc[1][n] = __builtin_amdgcn_mfma_f32_16x16x32_bf16(p10, bf[0][n], acc[1][n], 0, 0, 0);
#pragma unroll
      for (int n = 0; n < 4; ++n)
        acc[1][n] = __builtin_amdgcn_mfma_f32_16x16x32_bf16(p11, bf[1][n], acc[1][n], 0, 0, 0);
      __builtin_amdgcn_s_setprio(0);
      __builtin_amdgcn_s_barrier();
    }

    // ---------- phase 1: ds A(mf2,3); stage B(kt+1) ----------
    {
      short8 p00 = rdA(2, 0), p01 = rdA(2, 1), p10 = rdA(3, 0), p11 = rdA(3, 1);
      if (kt < 7) {
#pragma unroll
        for (int i = 0; i < 4; ++i)
          GLOAD16(bNext + soffB[i], bn + (i * 8 + wave) * 1024);
      }
      __builtin_amdgcn_s_barrier();
      asm volatile("s_waitcnt lgkmcnt(0)" ::: "memory");
      __builtin_amdgcn_sched_barrier(0);
      __builtin_amdgcn_s_setprio(1);
#pragma unroll
      for (int n = 0; n < 4; ++n)
        acc[2][n] = __builtin_amdgcn_mfma_f32_16x16x32_bf16(p00, bf[0][n], acc[2][n], 0, 0, 0);
#pragma unroll
      for (int n = 0; n < 4; ++n)
        acc[2][n] = __builtin_amdgcn_mfma_f32_16x16x32_bf16(p01, bf[1][n], acc[2][n], 0, 0, 0);
#pragma unroll
      for (int n = 0; n < 4; ++n)
        acc[3][n] = __builtin_amdgcn_mfma_f32_16x16x32_bf16(p10, bf[0][n], acc[3][n], 0, 0, 0);
#pragma unroll
      for (int n = 0; n < 4; ++n)
        acc[3][n] = __builtin_amdgcn_mfma_f32_16x16x32_bf16(p11, bf[1][n], acc[3][n], 0, 0, 0);
      __builtin_amdgcn_s_setprio(0);
      __builtin_amdgcn_s_barrier();
    }

    // ---------- phase 2: ds A(mf4,5) ----------
    {
      short8 p00 = rdA(4, 0), p01 = rdA(4, 1), p10 = rdA(5, 0), p11 = rdA(5, 1);
      __builtin_amdgcn_s_barrier();
      asm volatile("s_waitcnt lgkmcnt(0)" ::: "memory");
      __builtin_amdgcn_sched_barrier(0);
      __builtin_amdgcn_s_setprio(1);
#pragma unroll
      for (int n = 0; n < 4; ++n)
        acc[4][n] = __builtin_amdgcn_mfma_f32_16x16x32_bf16(p00, bf[0][n], acc[4][n], 0, 0, 0);
#pragma unroll
      for (int n = 0; n < 4; ++n)
        acc[4][n] = __builtin_amdgcn_mfma_f32_16x16x32_bf16(p01, bf[1][n], acc[4][n], 0, 0, 0);
#pragma unroll
      for (int n = 0; n < 4; ++n)
        acc[5][n] = __builtin_amdgcn_mfma_f32_16x16x32_bf16(p10, bf[0][n], acc[5][n], 0, 0, 0);
#pragma unroll
      for (int n = 0; n < 4; ++n)
        acc[5][n] = __builtin_amdgcn_mfma_f32_16x16x32_bf16(p11, bf[1][n], acc[5][n], 0, 0, 0);
      __builtin_amdgcn_s_setprio(0);
      __builtin_amdgcn_s_barrier();
    }

    // ---------- phase 3: ds A(mf6,7); vmcnt(0) for kt+1 readiness ----------
    {
      short8 p00 = rdA(6, 0), p01 = rdA(6, 1), p10 = rdA(7, 0), p11 = rdA(7, 1);
      if (kt < 7)
        asm volatile("s_waitcnt vmcnt(0)" ::: "memory");   // issued >=2 phases ago
      __builtin_amdgcn_s_barrier();
      asm volatile("s_waitcnt lgkmcnt(0)" ::: "memory");
      __builtin_amdgcn_sched_barrier(0);
      __builtin_amdgcn_s_setprio(1);
#pragma unroll
      for (int n = 0; n < 4; ++n)
        acc[6][n] = __builtin_amdgcn_mfma_f32_16x16x32_bf16(p00, bf[0][n], acc[6][n], 0, 0, 0);
#pragma unroll
      for (int n = 0; n < 4; ++n)
        acc[6][n] = __builtin_amdgcn_mfma_f32_16x16x32_bf16(p01, bf[1][n], acc[6][n], 0, 0, 0);
#pragma unroll
      for (int n = 0; n < 4; ++n)
        acc[7][n] = __builtin_amdgcn_mfma_f32_16x16x32_bf16(p10, bf[0][n], acc[7][n], 0, 0, 0);
#pragma unroll
      for (int n = 0; n < 4; ++n)
        acc[7][n] = __builtin_amdgcn_mfma_f32_16x16x32_bf16(p11, bf[1][n], acc[7][n], 0, 0, 0);
      __builtin_amdgcn_s_setprio(0);
      __builtin_amdgcn_s_barrier();
    }
  }

  // epilogue: bias+relu -> Wt-dot -> col reduce -> wn reduce -> gate -> atomicAdd
  float bev[4], wtv[2][4];
#pragma unroll
  for (int n = 0; n < 4; ++n) bev[n] = be[e * 256 + wn * 64 + n * 16 + row16];
#pragma unroll
  for (int t = 0; t < 2; ++t)
#pragma unroll
    for (int n = 0; n < 4; ++n) wtv[t][n] = Wt[t * 256 + wn * 64 + n * 16 + row16];

#pragma unroll
  for (int mf = 0; mf < 8; ++mf) {
#pragma unroll
    for (int j = 0; j < 4; ++j) {
      float p0 = 0.f, p1 = 0.f;
#pragma unroll
      for (int n = 0; n < 4; ++n) {
        float r = fmaxf(acc[mf][n][j] + bev[n], 0.f);
        p0 = fmaf(r, wtv[0][n], p0);
        p1 = fmaf(r, wtv[1][n], p1);
      }
      p0 += __shfl_xor(p0, 1); p1 += __shfl_xor(p1, 1);
      p0 += __shfl_xor(p0, 2); p1 += __shfl_xor(p1, 2);
      p0 += __shfl_xor(p0, 4); p1 += __shfl_xor(p1, 4);
      p0 += __shfl_xor(p0, 8); p1 += __shfl_xor(p1, 8);
      if (row16 == 0) {
        int rw = wm * 128 + mf * 16 + kgrp * 4 + j;
        red_lds[wn][rw][0] = p0;
        red_lds[wn][rw][1] = p1;
      }
    }
  }
  __syncthreads();

  {
    int row = tid >> 1, t = tid & 1;
    float s = red_lds[0][row][t] + red_lds[1][row][t]
            + red_lds[2][row][t] + red_lds[3][row][t];
    float g = gates_ws[(t * 8 + e) * BS + mt * 256 + row];
    atomicAdd(&acc_ws[t * BS + mt * 256 + row], s * g);
  }
}

__global__ void finalize(const float* __restrict__ acc_ws, const float* __restrict__ bt,
                         float* __restrict__ out) {
  int i = blockIdx.x * 256 + threadIdx.x;   // 65536
  int t = i >> 15;
  float s = fmaxf(acc_ws[i] + bt[t], 0.f);
  out[i] = 1.f / (1.f + __expf(-s));
}

extern "C" void kernel_launch(void* const* d_in, const int* in_sizes, int n_in,
                              void* d_out, int out_size, void* d_ws, size_t ws_size,
                              hipStream_t stream) {
  const float* xv = (const float*)d_in[0];
  const float* We = (const float*)d_in[1];
  const float* be = (const float*)d_in[2];
  const float* Wg = (const float*)d_in[3];
  const float* bg = (const float*)d_in[4];
  const float* Wt = (const float*)d_in[5];
  const float* bt = (const float*)d_in[6];
  float* out = (float*)d_out;

  unsigned char* ws = (unsigned char*)d_ws;
  unsigned short* WeT      = (unsigned short*)(ws);                     // 2 MiB
  unsigned short* WgT      = (unsigned short*)(ws + (2u << 20));        // 16 KiB
  unsigned short* Abf      = (unsigned short*)(ws + (4u << 20));        // 32 MiB
  float*          gates_ws = (float*)(ws + (36u << 20));                // 2 MiB
  float*          acc_ws   = (float*)(ws + (38u << 20));                // 256 KiB

  hipMemsetAsync(acc_ws, 0, 2 * BS * sizeof(float), stream);
  prep_weT<<<512, 256, 0, stream>>>(We, WeT);
  prep_wgT<<<16, 64, 0, stream>>>(Wg, WgT);
  conv_gates<<<512, 256, 0, stream>>>(xv, WgT, bg, Abf, gates_ws);
  mmoe_main<<<1024, 512, 0, stream>>>(Abf, WeT, gates_ws, be, Wt, acc_ws);
  finalize<<<256, 256, 0, stream>>>(acc_ws, bt, out);
}